// Round 18
// baseline (287.514 us; speedup 1.0000x reference)
//
#include <hip/hip_runtime.h>

// ChromaSelfAttention on MI355X (gfx950).  [R18 = R17 + deeper issue-spreading]
// Pipeline: cvt x->f16 | transpose-cvt W->W^T f16 | QKV GEMM + output GEMM
//           (128x256/BK64 pinned 2-phase dbuf; staging split A@top + B half in
//           each MFMA phase (m196 fine-interleave); counted vmcnt(2); XCD swizzle,
//           T2 swizzle, T5 setprio; z==2 epilogue writes V^T via LDS transpose)
//           | flash attention v6 (8 waves x 32 q-rows, 3-buffer ring depth-2,
//           K-stage post-barrier / V-stage post-QK^T, swapped QK^T, register P,
//           defer-max, XCD swizzle).
// fp16 operands, fp32 accumulation. Softmax scale*log2(e) folded into Q projection.

typedef _Float16 f16;
typedef __attribute__((ext_vector_type(8))) _Float16 f16x8;
typedef __attribute__((ext_vector_type(4))) _Float16 f16x4;
typedef __attribute__((ext_vector_type(4))) float f32x4;
typedef __attribute__((ext_vector_type(4))) unsigned int u32x4;

#define QSCALE (0.08838834764831845f * 1.4426950408889634f)  // d^-0.5 * log2(e)
#define SWZ3(r) (((r) & 3) | (((r) >> 1) & 4))  // attn K-tile swizzle (256B rows)
#define SWZV(r) ((r) & 7)                       // attn V-tile swizzle (128B rows)

static __device__ __forceinline__ void gload16(void* lds, const void* g) {
  __builtin_amdgcn_global_load_lds(
      (__attribute__((address_space(1))) void*)g,
      (__attribute__((address_space(3))) void*)lds, 16, 0, 0);
}

// ---------------- fp32 -> fp16 conversion of x_q/x_k/x_v (z selects) -------
__global__ __launch_bounds__(256) void cvt_x_kernel(
    const float* __restrict__ x0, const float* __restrict__ x1,
    const float* __restrict__ x2, f16* __restrict__ out) {
  const float* x = blockIdx.z == 0 ? x0 : (blockIdx.z == 1 ? x1 : x2);
  f16* o = out + (size_t)blockIdx.z * 8388608;
  size_t i = ((size_t)blockIdx.x * 256 + threadIdx.x) * 8;
  f32x4 a = *(const f32x4*)(x + i);
  f32x4 b = *(const f32x4*)(x + i + 4);
  f16x8 r;
  r[0] = (f16)a[0]; r[1] = (f16)a[1]; r[2] = (f16)a[2]; r[3] = (f16)a[3];
  r[4] = (f16)b[0]; r[5] = (f16)b[1]; r[6] = (f16)b[2]; r[7] = (f16)b[3];
  *(f16x8*)(o + i) = r;
}

// -------- W [K=2048][N=2048] f32 -> W^T [N][K] f16 (z: Wq,Wk,Wv,Wo) --------
__global__ __launch_bounds__(256) void cvt_w_kernel(
    const float* __restrict__ w0, const float* __restrict__ w1,
    const float* __restrict__ w2, const float* __restrict__ w3,
    f16* __restrict__ out) {
  const float* W = blockIdx.z == 0 ? w0 : blockIdx.z == 1 ? w1
                 : blockIdx.z == 2 ? w2 : w3;
  f16* WT = out + (size_t)blockIdx.z * 4194304;
  __shared__ f16 tile[64][68];  // +4 pad
  const int tx = threadIdx.x & 15, ty = threadIdx.x >> 4;
  const int k0 = blockIdx.y * 64, n0 = blockIdx.x * 64;
#pragma unroll
  for (int i = 0; i < 4; ++i) {
    int r = ty + i * 16;  // local k
    f32x4 v = *(const f32x4*)(W + (size_t)(k0 + r) * 2048 + n0 + tx * 4);
    tile[r][tx * 4 + 0] = (f16)v[0]; tile[r][tx * 4 + 1] = (f16)v[1];
    tile[r][tx * 4 + 2] = (f16)v[2]; tile[r][tx * 4 + 3] = (f16)v[3];
  }
  __syncthreads();
#pragma unroll
  for (int i = 0; i < 4; ++i) {
    int n = ty + i * 16;  // local n
    f16x4 o;
    o[0] = tile[tx * 4 + 0][n]; o[1] = tile[tx * 4 + 1][n];
    o[2] = tile[tx * 4 + 2][n]; o[3] = tile[tx * 4 + 3][n];
    *(f16x4*)(WT + (size_t)(n0 + n) * 2048 + k0 + tx * 4) = o;
  }
}

// ---------------- shared 128x256 GEMM template (fine-interleaved v2) -------
// C = A[M,2048] @ Bt[2048,*]^T. BM=128, BN=256, BK=64, 32 K-tiles.
// 8 waves (2M x 4N), per-wave C = 64x64 (acc[4][4]). LDS 96 KiB dbuf.
// Staging for kt+1 split 3 ways: 2 A-gloads @ iter top (pre-wait), 2 B-gloads
// inside phase 0, 2 B-gloads inside phase 1 -> memory-pipe issue spread across
// both MFMA phases (m196). Wait vmcnt(2): queue at top of kt holds kt's 4 B +
// kt+1's 2 A; <=2 outstanding lands all of tile kt. WAR as in R8.
// MODE 0: QKV -> head-split f16 [b,h,l,d] + bias (+QSCALE z==0);
//         z==2 writes V^T [b,h,d,l] via LDS transpose (tr_v fused).
// MODE 1: out -> f32 [4096,2048] + bias. Grids: 768 / 256, XCD-chunked.
template <int MODE>
__global__ __launch_bounds__(512, 2) void gemm128_kernel(
    const f16* __restrict__ Abase, const f16* __restrict__ Btbase,
    void* __restrict__ Obase, const float* __restrict__ b0,
    const float* __restrict__ b1, const float* __restrict__ b2) {
  const int lid = blockIdx.x;
  int bn, bm, z;
  if (MODE == 0) {
    const int logi = (lid & 7) * 96 + (lid >> 3);  // bijective, 768%8==0
    bn = logi & 7; bm = (logi >> 3) & 31; z = logi >> 8;
  } else {
    const int logi = (lid & 7) * 32 + (lid >> 3);  // bijective, 256%8==0
    bn = logi & 7; bm = logi >> 3; z = 0;
  }
  const f16* A  = Abase  + (size_t)z * 8388608;
  const f16* Bt = Btbase + (size_t)z * 4194304;
  const float* bias = z == 0 ? b0 : (z == 1 ? b1 : b2);
  const float qsc = (MODE == 0 && z == 0) ? QSCALE : 1.0f;
  const int tid = threadIdx.x, lane = tid & 63, w = tid >> 6;  // 8 waves
  const int wm = w >> 2, wn = w & 3;
  const int l15 = lane & 15, lg = lane >> 4;
  __shared__ alignas(16) char smb[98304];  // buf c: A @ c*49152 (16K), B @ +16384 (32K)

  f32x4 acc[4][4];
#pragma unroll
  for (int i = 0; i < 4; ++i)
#pragma unroll
    for (int j = 0; j < 4; ++j) acc[i][j] = (f32x4)0.f;

#define ASTAGE(KT, C_)                                                        \
  {                                                                           \
    char* Ab_ = smb + (C_) * 49152;                                           \
    _Pragma("unroll") for (int p = 0; p < 2; ++p) {                           \
      int L = p * 8192 + tid * 16;                                            \
      int row = L >> 7, pcol = L & 127;                                       \
      int scol = pcol ^ ((row & 7) << 4);                                     \
      gload16(Ab_ + L,                                                        \
              (const char*)A + ((size_t)(bm * 128 + row) * 2048 + (KT) * 64) * 2 + scol); \
    }                                                                         \
  }

#define BSTAGE_H(KT, C_, PH)                                                  \
  {                                                                           \
    char* Bb_ = smb + (C_) * 49152 + 16384;                                   \
    _Pragma("unroll") for (int p = (PH) * 2; p < (PH) * 2 + 2; ++p) {         \
      int L = p * 8192 + tid * 16;                                            \
      int row = L >> 7, pcol = L & 127;                                       \
      int scol = pcol ^ ((row & 7) << 4);                                     \
      gload16(Bb_ + L,                                                        \
              (const char*)Bt + ((size_t)(bn * 256 + row) * 2048 + (KT) * 64) * 2 + scol); \
    }                                                                         \
  }

#define GREADS(H)                                                             \
  _Pragma("unroll") for (int i = 0; i < 4; ++i) {                             \
    int row = wm * 64 + i * 16 + l15;                                         \
    af[H][i] = *(const f16x8*)(Ab + row * 128 +                               \
                               (((H) * 64 + lg * 16) ^ ((row & 7) << 4)));    \
  }                                                                           \
  _Pragma("unroll") for (int j = 0; j < 4; ++j) {                             \
    int row = wn * 64 + j * 16 + l15;                                         \
    bf[H][j] = *(const f16x8*)(Bb + row * 128 +                               \
                               (((H) * 64 + lg * 16) ^ ((row & 7) << 4)));    \
  }

#define GMFMA(H)                                                              \
  __builtin_amdgcn_s_setprio(1);                                              \
  _Pragma("unroll") for (int i = 0; i < 4; ++i)                               \
    _Pragma("unroll") for (int j = 0; j < 4; ++j)                             \
      acc[i][j] = __builtin_amdgcn_mfma_f32_16x16x32_f16(                     \
          af[H][i], bf[H][j], acc[i][j], 0, 0, 0);                            \
  __builtin_amdgcn_s_setprio(0);

  ASTAGE(0, 0);
  BSTAGE_H(0, 0, 0);
  BSTAGE_H(0, 0, 1);
#pragma unroll 1
  for (int kt = 0; kt < 32; ++kt) {
    const int c = kt & 1;
    if (kt < 31) {
      ASTAGE(kt + 1, c ^ 1);  // 2 loads; stay in flight across the wait
      asm volatile("s_waitcnt vmcnt(2)" ::: "memory");  // tile kt fully landed
    } else {
      asm volatile("s_waitcnt vmcnt(0)" ::: "memory");
    }
    __builtin_amdgcn_s_barrier();  // tile kt visible to all waves

    const char* Ab = smb + c * 49152;
    const char* Bb = Ab + 16384;
    f16x8 af[2][4], bf[2][4];
    // phase 0 (K-half 0): reads, then first half of kt+1's B-stage
    GREADS(0);
    if (kt < 31) BSTAGE_H(kt + 1, c ^ 1, 0);
    asm volatile("s_waitcnt lgkmcnt(0)" ::: "memory");
    __builtin_amdgcn_sched_barrier(0);
    GMFMA(0);
    // phase 1 (K-half 1): reads + second half of B-stage (overlap MFMA(1)/top)
    GREADS(1);
    if (kt < 31) BSTAGE_H(kt + 1, c ^ 1, 1);
    __builtin_amdgcn_sched_barrier(0);
    __builtin_amdgcn_s_barrier();
    asm volatile("s_waitcnt lgkmcnt(0)" ::: "memory");
    __builtin_amdgcn_sched_barrier(0);
    GMFMA(1);
  }

  // epilogue
  if (MODE == 0 && z == 2) {
    // V: write V^T [b,h,d,l] directly (tr_v fused). LDS transpose:
    // stage tile as [d_local(256)][l_local(128)] f16, pad row to 272B.
    char* lt = smb;  // 256*272 = 69632 B <= 98304
    __syncthreads();  // all waves' phase-1 ds_reads complete before overwrite
#pragma unroll
    for (int i = 0; i < 4; ++i)
#pragma unroll
      for (int j = 0; j < 4; ++j) {
        int dl = wn * 64 + j * 16 + l15;
        float bv = bias[bn * 256 + dl];
        f16x4 vv;
#pragma unroll
        for (int r = 0; r < 4; ++r) vv[r] = (f16)(acc[i][j][r] + bv);
        *(f16x4*)(lt + dl * 272 + (wm * 64 + i * 16 + lg * 4) * 2) = vv;
      }
    __syncthreads();
    f16* Vt = (f16*)Obase + (size_t)2 * 8388608;  // own output slot, no alias
    const int b_ = bm >> 4;
    const int lb = (bm & 15) * 128;
#pragma unroll
    for (int cpar = 0; cpar < 8; ++cpar) {
      int cid = cpar * 512 + tid;          // 4096 chunks = 256 d x 16 x 16B
      int dl = cid >> 4, o8 = cid & 15;
      f16x8 vv = *(const f16x8*)(lt + dl * 272 + o8 * 16);
      int dg = bn * 256 + dl, h = dg >> 7, dh = dg & 127;
      *(f16x8*)(Vt + (size_t)(b_ * 16 + h) * 262144 + (size_t)dh * 2048 +
                lb + o8 * 8) = vv;
    }
  } else if (MODE == 0) {
    f16* Oz = (f16*)Obase + (size_t)z * 8388608;
#pragma unroll
    for (int i = 0; i < 4; ++i)
#pragma unroll
      for (int j = 0; j < 4; ++j) {
        int col = bn * 256 + wn * 64 + j * 16 + l15;
        int h = col >> 7, d = col & 127;
        float bv = bias[col];
#pragma unroll
        for (int r = 0; r < 4; ++r) {
          int rowg = bm * 128 + wm * 64 + i * 16 + lg * 4 + r;
          int b_ = rowg >> 11, lpos = rowg & 2047;
          Oz[(size_t)(b_ * 16 + h) * 262144 + (size_t)lpos * 128 + d] =
              (f16)((acc[i][j][r] + bv) * qsc);
        }
      }
  } else {
    float* Out = (float*)Obase;
#pragma unroll
    for (int i = 0; i < 4; ++i)
#pragma unroll
      for (int j = 0; j < 4; ++j) {
        int col = bn * 256 + wn * 64 + j * 16 + l15;
        float bv = bias[col];
#pragma unroll
        for (int r = 0; r < 4; ++r) {
          int rowg = bm * 128 + wm * 64 + i * 16 + lg * 4 + r;
          Out[(size_t)rowg * 2048 + col] = acc[i][j][r] + bv;
        }
      }
  }
#undef ASTAGE
#undef BSTAGE_H
#undef GREADS
#undef GMFMA
}

// ---------------- flash attention v6b (8 waves x 32 q-rows, QBLK=256) ------
// 512 threads, KVBLK=64, 3-buffer ring (96KB) with depth-2 prefetch; staging
// for tile t+2 split: K-loads post-barrier, V-loads post-QK^T (issue spread,
// m196 analog). Counted per-wave vmcnt(4): tile t landed, t+1 in flight.
// Grid 256 = exactly 1 block/CU. Swapped QK^T (mf=2); zero-shuffle register P;
// defer-max THR=8; XCD-chunked swizzle.
__global__ __launch_bounds__(512, 2) void attn_kernel(
    const f16* __restrict__ q, const f16* __restrict__ k,
    const f16* __restrict__ vt, f16* __restrict__ o) {
  const int orig = blockIdx.x;                        // [0,256)
  const int swz = (orig & 7) * 32 + (orig >> 3);      // bijective (256%8==0)
  const int qt = swz & 7, bh = swz >> 3;              // 8 q-tiles of 256 rows
  const int tid = threadIdx.x, lane = tid & 63, w = tid >> 6;  // w in [0,8)
  const int l15 = lane & 15, lg = lane >> 4;
  const f16* Qb = q + (size_t)bh * 262144 + (size_t)qt * 256 * 128;
  const char* Kb = (const char*)(k + (size_t)bh * 262144);
  const char* Vtb = (const char*)(vt + (size_t)bh * 262144);
  __shared__ alignas(16) char sm[98304];  // buf b: K @ b*32768 (16K), V @ +16384

  // Q fragments (B-operand): wave w owns q-rows w*32+mf*16+l15
  f16x8 qf[2][4];
#pragma unroll
  for (int mf = 0; mf < 2; ++mf)
#pragma unroll
    for (int ks = 0; ks < 4; ++ks)
      qf[mf][ks] = *(const f16x8*)(Qb + (w * 32 + mf * 16 + l15) * 128 + ks * 32 + lg * 8);

  f32x4 oacc[2][8];
  float mrow[2], ps[2];
#pragma unroll
  for (int mf = 0; mf < 2; ++mf) {
#pragma unroll
    for (int df = 0; df < 8; ++df) oacc[mf][df] = (f32x4)0.f;
    mrow[mf] = -1e30f; ps[mf] = 0.f;
  }
  const int rA = ((l15 >> 2) << 3) + (l15 & 3);  // K-frag row permutation base

#define KSTAGE(T, B)                                                         \
  {                                                                          \
    char* Ks_ = sm + (B) * 32768;                                            \
    _Pragma("unroll") for (int i = 0; i < 2; ++i) {                          \
      int c = i * 8 + w;                                                     \
      int phys = c * 1024 + lane * 16;                                       \
      int row = phys >> 8, pcol = phys & 255;                                \
      int lcol = pcol ^ (SWZ3(row) << 4);                                    \
      gload16(Ks_ + c * 1024, Kb + (size_t)((T) * 64 + row) * 256 + lcol);   \
    }                                                                        \
  }

#define VSTAGE(T, B)                                                         \
  {                                                                          \
    char* Vs_ = sm + (B) * 32768 + 16384;                                    \
    _Pragma("unroll") for (int i = 0; i < 2; ++i) {                          \
      int c = i * 8 + w;                                                     \
      int phys = c * 1024 + lane * 16;                                       \
      int row = phys >> 7, pcol = phys & 127;                                \
      int lcol = pcol ^ (SWZV(row) << 4);                                    \
      gload16(Vs_ + c * 1024, Vtb + (size_t)row * 4096 + (T) * 128 + lcol);  \
    }                                                                        \
  }

  KSTAGE(0, 0); VSTAGE(0, 0);
  KSTAGE(1, 1); VSTAGE(1, 1);
  int cur = 0;      // buffer of tile t
  int nxt2 = 2;     // buffer for tile t+2
  for (int t = 0; t < 32; ++t) {
    // per-wave: tile t's 4 loads done; tile t+1's 4 stay in flight
    if (t < 31)
      asm volatile("s_waitcnt vmcnt(4)" ::: "memory");
    else
      asm volatile("s_waitcnt vmcnt(0)" ::: "memory");
    __builtin_amdgcn_s_barrier();  // all waves: tile t in LDS; buf nxt2 free
    if (t < 30) KSTAGE(t + 2, nxt2);  // K first (consumed first next-next iter)
    const char* Ks = sm + cur * 32768;
    const char* Vs = Ks + 16384;

    // ---- QK^T swapped: s[mf][nf] = S[kv'][q] -------------------------------
    f32x4 s[2][4];
#pragma unroll
    for (int mf = 0; mf < 2; ++mf)
#pragma unroll
      for (int nf = 0; nf < 4; ++nf) s[mf][nf] = (f32x4)0.f;
    __builtin_amdgcn_s_setprio(1);
#pragma unroll
    for (int ks = 0; ks < 4; ++ks) {
      f16x8 kf[4];
#pragma unroll
      for (int nf = 0; nf < 4; ++nf) {
        int row = ((nf & 1) << 5) + ((nf >> 1) << 2) + rA;  // permuted kv row
        int colb = (ks * 64 + lg * 16) ^ (SWZ3(row) << 4);
        kf[nf] = *(const f16x8*)(Ks + row * 256 + colb);
      }
#pragma unroll
      for (int mf = 0; mf < 2; ++mf)
#pragma unroll
        for (int nf = 0; nf < 4; ++nf)
          s[mf][nf] = __builtin_amdgcn_mfma_f32_16x16x32_f16(kf[nf], qf[mf][ks], s[mf][nf], 0, 0, 0);
    }
    __builtin_amdgcn_s_setprio(0);
    if (t < 30) VSTAGE(t + 2, nxt2);  // V-issue overlaps softmax + PV

    // ---- online softmax (defer-max), P packed in registers -----------------
    unsigned int pk[2][2][4];  // [mf][kvs][word] -> PV A-frag direct
#pragma unroll
    for (int mf = 0; mf < 2; ++mf) {
      float m01 = fmaxf(fmaxf(s[mf][0][0], s[mf][0][1]),
                        fmaxf(s[mf][0][2], s[mf][0][3]));
      float m23 = fmaxf(fmaxf(s[mf][1][0], s[mf][1][1]),
                        fmaxf(s[mf][1][2], s[mf][1][3]));
      float m45 = fmaxf(fmaxf(s[mf][2][0], s[mf][2][1]),
                        fmaxf(s[mf][2][2], s[mf][2][3]));
      float m67 = fmaxf(fmaxf(s[mf][3][0], s[mf][3][1]),
                        fmaxf(s[mf][3][2], s[mf][3][3]));
      float mx = fmaxf(fmaxf(m01, m23), fmaxf(m45, m67));
      mx = fmaxf(mx, __shfl_xor(mx, 16));
      mx = fmaxf(mx, __shfl_xor(mx, 32));
      if (!__all(mx <= mrow[mf] + 8.f)) {  // rare after first tile
        float mnew = fmaxf(mrow[mf], mx);
        float sc = exp2f(mrow[mf] - mnew);
        mrow[mf] = mnew;
        ps[mf] *= sc;
#pragma unroll
        for (int r = 0; r < 4; ++r) {
          float scr = __shfl(sc, (lane & 48) | (lg * 4 + r));
#pragma unroll
          for (int df = 0; df < 8; ++df) oacc[mf][df][r] *= scr;
        }
      }
      float m = mrow[mf];
      float psum = 0.f;
#pragma unroll
      for (int nf = 0; nf < 4; ++nf)
#pragma unroll
        for (int h = 0; h < 2; ++h) {
          float p0 = exp2f(s[mf][nf][2 * h] - m);
          float p1 = exp2f(s[mf][nf][2 * h + 1] - m);
          psum += p0 + p1;
          pk[mf][nf & 1][(nf >> 1) * 2 + h] =
              __builtin_bit_cast(unsigned int, __builtin_amdgcn_cvt_pkrtz(p0, p1));
        }
      ps[mf] += psum;  // cross-lane reduction deferred to epilogue
    }

    // ---- PV: oacc += P[32 x 64] @ V[64 x 128] ------------------------------
    __builtin_amdgcn_s_setprio(1);
#pragma unroll
    for (int kvs = 0; kvs < 2; ++kvs) {
      f16x8 pa[2];
#pragma unroll
      for (int mf = 0; mf < 2; ++mf)
        pa[mf] = __builtin_bit_cast(f16x8, *(const u32x4*)pk[mf][kvs]);
#pragma unroll
      for (int df = 0; df < 8; ++df) {
        int row = df * 16 + l15;
        int colb = (kvs * 64 + lg * 16) ^ (SWZV(row) << 4);
        f16x8 vb = *(const f16x8*)(Vs + row * 128 + colb);
#pragma unroll
        for (int mf = 0; mf < 2; ++mf)
          oacc[mf][df] = __builtin_amdgcn_mfma_f32_16x16x32_f16(pa[mf], vb, oacc[mf][df], 0, 0, 0);
      }
    }
    __builtin_amdgcn_s_setprio(0);
    cur = cur == 2 ? 0 : cur + 1;
    nxt2 = nxt2 == 2 ? 0 : nxt2 + 1;
  }

  // epilogue: reduce l across lanes, normalize, write o [b,l,h*128+d] f16
  const int b_ = bh >> 4, h_ = bh & 15;
  f16* Ob = o + (size_t)b_ * 4194304 + (size_t)qt * 256 * 2048 + h_ * 128;
#pragma unroll
  for (int mf = 0; mf < 2; ++mf) {
    float lr = ps[mf];
    lr += __shfl_xor(lr, 16);
    lr += __shfl_xor(lr, 32);
    float inv = 1.f / lr;  // for q-row l15
#pragma unroll
    for (int r = 0; r < 4; ++r) {
      float invr = __shfl(inv, (lane & 48) | (lg * 4 + r));
      int rl = w * 32 + mf * 16 + lg * 4 + r;
#pragma unroll
      for (int df = 0; df < 8; ++df)
        Ob[(size_t)rl * 2048 + df * 16 + l15] = (f16)(oacc[mf][df][r] * invr);
    }
  }
#undef KSTAGE
#undef VSTAGE
}

// ---------------------------------------------------------------------------
extern "C" void kernel_launch(void* const* d_in, const int* in_sizes, int n_in,
                              void* d_out, int out_size, void* d_ws, size_t ws_size,
                              hipStream_t stream) {
  const float* xq = (const float*)d_in[0];
  const float* xk = (const float*)d_in[1];
  const float* xv = (const float*)d_in[2];
  const float* Wq = (const float*)d_in[3];
  const float* bq = (const float*)d_in[4];
  const float* Wk = (const float*)d_in[5];
  const float* bk = (const float*)d_in[6];
  const float* Wv = (const float*)d_in[7];
  const float* bv = (const float*)d_in[8];
  const float* Wo = (const float*)d_in[9];
  const float* bo = (const float*)d_in[10];

  // ws layout (bytes), total 128 MiB:
  //   [0,50331648)        xh: x_q/x_k/x_v f16 (3 x 16 MiB)
  //   [50331648,83886080) wt: WqT/WkT/WvT/WoT f16 (4 x 8 MiB)
  //   [83886080,134217728) qkv: q/k/v^T head-split f16 (3 x 16 MiB)
  //       (z==2 slot holds V^T [b,h,d,l] -- written directly by the GEMM)
  //   oatt aliases xh_k region (dead after QKV GEMM).
  char* ws = (char*)d_ws;
  f16* xh   = (f16*)(ws);
  f16* wt   = (f16*)(ws + 50331648);
  f16* qkv  = (f16*)(ws + 83886080);
  f16* oatt = (f16*)(ws + 16777216);  // alias: x_k f16 region
  float* outp = (float*)d_out;

  hipLaunchKernelGGL(cvt_x_kernel, dim3(4096, 1, 3), dim3(256), 0, stream,
                     xq, xk, xv, xh);
  hipLaunchKernelGGL(cvt_w_kernel, dim3(32, 32, 4), dim3(256), 0, stream,
                     Wq, Wk, Wv, Wo, wt);
  hipLaunchKernelGGL((gemm128_kernel<0>), dim3(768), dim3(512), 0, stream,
                     xh, wt, (void*)qkv, bq, bk, bv);
  hipLaunchKernelGGL(attn_kernel, dim3(256), dim3(512), 0, stream,
                     qkv, qkv + (size_t)8388608, qkv + (size_t)2 * 8388608, oatt);
  hipLaunchKernelGGL((gemm128_kernel<1>), dim3(256), dim3(512), 0, stream,
                     oatt, wt + (size_t)3 * 4194304, (void*)outp, bo, bo, bo);
}

// Round 19
// 276.622 us; speedup vs baseline: 1.0394x; 1.0394x over previous
//
#include <hip/hip_runtime.h>

// ChromaSelfAttention on MI355X (gfx950).  [R19 = R17 champion, restored]
// Pipeline: cvt x->f16 | transpose-cvt W->W^T f16 | QKV GEMM + output GEMM
//           (128x256/BK64 pinned 2-phase dbuf; staging SPLIT per m196: A-gloads
//           at top, B-gloads inside phase 0 -> memory pipe fed during MFMA;
//           counted vmcnt(2); XCD swizzle, T2 swizzle, T5 setprio; z==2 epilogue
//           writes V^T via LDS transpose) | flash attention v6 (8 waves x 32
//           q-rows, 3-buffer ring depth-2, swapped QK^T, register P, defer-max).
// fp16 operands, fp32 accumulation. Softmax scale*log2(e) folded into Q projection.

typedef _Float16 f16;
typedef __attribute__((ext_vector_type(8))) _Float16 f16x8;
typedef __attribute__((ext_vector_type(4))) _Float16 f16x4;
typedef __attribute__((ext_vector_type(4))) float f32x4;
typedef __attribute__((ext_vector_type(4))) unsigned int u32x4;

#define QSCALE (0.08838834764831845f * 1.4426950408889634f)  // d^-0.5 * log2(e)
#define SWZ3(r) (((r) & 3) | (((r) >> 1) & 4))  // attn K-tile swizzle (256B rows)
#define SWZV(r) ((r) & 7)                       // attn V-tile swizzle (128B rows)

static __device__ __forceinline__ void gload16(void* lds, const void* g) {
  __builtin_amdgcn_global_load_lds(
      (__attribute__((address_space(1))) void*)g,
      (__attribute__((address_space(3))) void*)lds, 16, 0, 0);
}

// ---------------- fp32 -> fp16 conversion of x_q/x_k/x_v (z selects) -------
__global__ __launch_bounds__(256) void cvt_x_kernel(
    const float* __restrict__ x0, const float* __restrict__ x1,
    const float* __restrict__ x2, f16* __restrict__ out) {
  const float* x = blockIdx.z == 0 ? x0 : (blockIdx.z == 1 ? x1 : x2);
  f16* o = out + (size_t)blockIdx.z * 8388608;
  size_t i = ((size_t)blockIdx.x * 256 + threadIdx.x) * 8;
  f32x4 a = *(const f32x4*)(x + i);
  f32x4 b = *(const f32x4*)(x + i + 4);
  f16x8 r;
  r[0] = (f16)a[0]; r[1] = (f16)a[1]; r[2] = (f16)a[2]; r[3] = (f16)a[3];
  r[4] = (f16)b[0]; r[5] = (f16)b[1]; r[6] = (f16)b[2]; r[7] = (f16)b[3];
  *(f16x8*)(o + i) = r;
}

// -------- W [K=2048][N=2048] f32 -> W^T [N][K] f16 (z: Wq,Wk,Wv,Wo) --------
__global__ __launch_bounds__(256) void cvt_w_kernel(
    const float* __restrict__ w0, const float* __restrict__ w1,
    const float* __restrict__ w2, const float* __restrict__ w3,
    f16* __restrict__ out) {
  const float* W = blockIdx.z == 0 ? w0 : blockIdx.z == 1 ? w1
                 : blockIdx.z == 2 ? w2 : w3;
  f16* WT = out + (size_t)blockIdx.z * 4194304;
  __shared__ f16 tile[64][68];  // +4 pad
  const int tx = threadIdx.x & 15, ty = threadIdx.x >> 4;
  const int k0 = blockIdx.y * 64, n0 = blockIdx.x * 64;
#pragma unroll
  for (int i = 0; i < 4; ++i) {
    int r = ty + i * 16;  // local k
    f32x4 v = *(const f32x4*)(W + (size_t)(k0 + r) * 2048 + n0 + tx * 4);
    tile[r][tx * 4 + 0] = (f16)v[0]; tile[r][tx * 4 + 1] = (f16)v[1];
    tile[r][tx * 4 + 2] = (f16)v[2]; tile[r][tx * 4 + 3] = (f16)v[3];
  }
  __syncthreads();
#pragma unroll
  for (int i = 0; i < 4; ++i) {
    int n = ty + i * 16;  // local n
    f16x4 o;
    o[0] = tile[tx * 4 + 0][n]; o[1] = tile[tx * 4 + 1][n];
    o[2] = tile[tx * 4 + 2][n]; o[3] = tile[tx * 4 + 3][n];
    *(f16x4*)(WT + (size_t)(n0 + n) * 2048 + k0 + tx * 4) = o;
  }
}

// ---------------- shared 128x256 GEMM template (fine-interleaved) ----------
// C = A[M,2048] @ Bt[2048,*]^T. BM=128, BN=256, BK=64, 32 K-tiles.
// 8 waves (2M x 4N), per-wave C = 64x64 (acc[4][4]). LDS 96 KiB dbuf.
// Staging for tile kt+1 SPLIT (m196 fine-interleave): 2 A-gloads at iter top
// (pre-wait), 4 B-gloads inside phase 0 (post-ds_read, pre-MFMA) -> memory
// pipe stays fed during MFMA phases. Wait = vmcnt(2): at top of kt the queue
// is [kt's 4 B, kt+1's 2 A]; forcing <=2 outstanding lands all of tile kt.
// WAR: stores to buf c^1 are issued after the top barrier that every wave
// reached only after lgkm-draining its tile kt-1 reads (same proof as R8).
// MODE 0: QKV -> head-split f16 [b,h,l,d] + bias (+QSCALE z==0);
//         z==2 writes V^T [b,h,d,l] via LDS transpose (tr_v fused).
// MODE 1: out -> f32 [4096,2048] + bias. Grids: 768 / 256, XCD-chunked.
template <int MODE>
__global__ __launch_bounds__(512, 2) void gemm128_kernel(
    const f16* __restrict__ Abase, const f16* __restrict__ Btbase,
    void* __restrict__ Obase, const float* __restrict__ b0,
    const float* __restrict__ b1, const float* __restrict__ b2) {
  const int lid = blockIdx.x;
  int bn, bm, z;
  if (MODE == 0) {
    const int logi = (lid & 7) * 96 + (lid >> 3);  // bijective, 768%8==0
    bn = logi & 7; bm = (logi >> 3) & 31; z = logi >> 8;
  } else {
    const int logi = (lid & 7) * 32 + (lid >> 3);  // bijective, 256%8==0
    bn = logi & 7; bm = logi >> 3; z = 0;
  }
  const f16* A  = Abase  + (size_t)z * 8388608;
  const f16* Bt = Btbase + (size_t)z * 4194304;
  const float* bias = z == 0 ? b0 : (z == 1 ? b1 : b2);
  const float qsc = (MODE == 0 && z == 0) ? QSCALE : 1.0f;
  const int tid = threadIdx.x, lane = tid & 63, w = tid >> 6;  // 8 waves
  const int wm = w >> 2, wn = w & 3;
  const int l15 = lane & 15, lg = lane >> 4;
  __shared__ alignas(16) char smb[98304];  // buf c: A @ c*49152 (16K), B @ +16384 (32K)

  f32x4 acc[4][4];
#pragma unroll
  for (int i = 0; i < 4; ++i)
#pragma unroll
    for (int j = 0; j < 4; ++j) acc[i][j] = (f32x4)0.f;

#define ASTAGE(KT, C_)                                                        \
  {                                                                           \
    char* Ab_ = smb + (C_) * 49152;                                           \
    _Pragma("unroll") for (int p = 0; p < 2; ++p) {                           \
      int L = p * 8192 + tid * 16;                                            \
      int row = L >> 7, pcol = L & 127;                                       \
      int scol = pcol ^ ((row & 7) << 4);                                     \
      gload16(Ab_ + L,                                                        \
              (const char*)A + ((size_t)(bm * 128 + row) * 2048 + (KT) * 64) * 2 + scol); \
    }                                                                         \
  }

#define BSTAGE(KT, C_)                                                        \
  {                                                                           \
    char* Bb_ = smb + (C_) * 49152 + 16384;                                   \
    _Pragma("unroll") for (int p = 0; p < 4; ++p) {                           \
      int L = p * 8192 + tid * 16;                                            \
      int row = L >> 7, pcol = L & 127;                                       \
      int scol = pcol ^ ((row & 7) << 4);                                     \
      gload16(Bb_ + L,                                                        \
              (const char*)Bt + ((size_t)(bn * 256 + row) * 2048 + (KT) * 64) * 2 + scol); \
    }                                                                         \
  }

#define GREADS(H)                                                             \
  _Pragma("unroll") for (int i = 0; i < 4; ++i) {                             \
    int row = wm * 64 + i * 16 + l15;                                         \
    af[H][i] = *(const f16x8*)(Ab + row * 128 +                               \
                               (((H) * 64 + lg * 16) ^ ((row & 7) << 4)));    \
  }                                                                           \
  _Pragma("unroll") for (int j = 0; j < 4; ++j) {                             \
    int row = wn * 64 + j * 16 + l15;                                         \
    bf[H][j] = *(const f16x8*)(Bb + row * 128 +                               \
                               (((H) * 64 + lg * 16) ^ ((row & 7) << 4)));    \
  }

#define GMFMA(H)                                                              \
  __builtin_amdgcn_s_setprio(1);                                              \
  _Pragma("unroll") for (int i = 0; i < 4; ++i)                               \
    _Pragma("unroll") for (int j = 0; j < 4; ++j)                             \
      acc[i][j] = __builtin_amdgcn_mfma_f32_16x16x32_f16(                     \
          af[H][i], bf[H][j], acc[i][j], 0, 0, 0);                            \
  __builtin_amdgcn_s_setprio(0);

  ASTAGE(0, 0);
  BSTAGE(0, 0);
#pragma unroll 1
  for (int kt = 0; kt < 32; ++kt) {
    const int c = kt & 1;
    if (kt < 31) {
      ASTAGE(kt + 1, c ^ 1);  // 2 loads; stay in flight across the wait
      asm volatile("s_waitcnt vmcnt(2)" ::: "memory");  // tile kt fully landed
    } else {
      asm volatile("s_waitcnt vmcnt(0)" ::: "memory");
    }
    __builtin_amdgcn_s_barrier();  // tile kt visible to all waves

    const char* Ab = smb + c * 49152;
    const char* Bb = Ab + 16384;
    f16x8 af[2][4], bf[2][4];
    // phase 0 (K-half 0): reads, then B-stage for kt+1 (issue overlaps MFMA)
    GREADS(0);
    if (kt < 31) BSTAGE(kt + 1, c ^ 1);
    asm volatile("s_waitcnt lgkmcnt(0)" ::: "memory");
    __builtin_amdgcn_sched_barrier(0);
    GMFMA(0);
    // phase 1 (K-half 1): reads pre-barrier overlap other waves' phase-0 MFMA
    GREADS(1);
    __builtin_amdgcn_sched_barrier(0);
    __builtin_amdgcn_s_barrier();
    asm volatile("s_waitcnt lgkmcnt(0)" ::: "memory");
    __builtin_amdgcn_sched_barrier(0);
    GMFMA(1);
  }

  // epilogue
  if (MODE == 0 && z == 2) {
    // V: write V^T [b,h,d,l] directly (tr_v fused). LDS transpose:
    // stage tile as [d_local(256)][l_local(128)] f16, pad row to 272B.
    char* lt = smb;  // 256*272 = 69632 B <= 98304
    __syncthreads();  // all waves' phase-1 ds_reads complete before overwrite
#pragma unroll
    for (int i = 0; i < 4; ++i)
#pragma unroll
      for (int j = 0; j < 4; ++j) {
        int dl = wn * 64 + j * 16 + l15;
        float bv = bias[bn * 256 + dl];
        f16x4 vv;
#pragma unroll
        for (int r = 0; r < 4; ++r) vv[r] = (f16)(acc[i][j][r] + bv);
        *(f16x4*)(lt + dl * 272 + (wm * 64 + i * 16 + lg * 4) * 2) = vv;
      }
    __syncthreads();
    f16* Vt = (f16*)Obase + (size_t)2 * 8388608;  // own output slot, no alias
    const int b_ = bm >> 4;
    const int lb = (bm & 15) * 128;
#pragma unroll
    for (int cpar = 0; cpar < 8; ++cpar) {
      int cid = cpar * 512 + tid;          // 4096 chunks = 256 d x 16 x 16B
      int dl = cid >> 4, o8 = cid & 15;
      f16x8 vv = *(const f16x8*)(lt + dl * 272 + o8 * 16);
      int dg = bn * 256 + dl, h = dg >> 7, dh = dg & 127;
      *(f16x8*)(Vt + (size_t)(b_ * 16 + h) * 262144 + (size_t)dh * 2048 +
                lb + o8 * 8) = vv;
    }
  } else if (MODE == 0) {
    f16* Oz = (f16*)Obase + (size_t)z * 8388608;
#pragma unroll
    for (int i = 0; i < 4; ++i)
#pragma unroll
      for (int j = 0; j < 4; ++j) {
        int col = bn * 256 + wn * 64 + j * 16 + l15;
        int h = col >> 7, d = col & 127;
        float bv = bias[col];
#pragma unroll
        for (int r = 0; r < 4; ++r) {
          int rowg = bm * 128 + wm * 64 + i * 16 + lg * 4 + r;
          int b_ = rowg >> 11, lpos = rowg & 2047;
          Oz[(size_t)(b_ * 16 + h) * 262144 + (size_t)lpos * 128 + d] =
              (f16)((acc[i][j][r] + bv) * qsc);
        }
      }
  } else {
    float* Out = (float*)Obase;
#pragma unroll
    for (int i = 0; i < 4; ++i)
#pragma unroll
      for (int j = 0; j < 4; ++j) {
        int col = bn * 256 + wn * 64 + j * 16 + l15;
        float bv = bias[col];
#pragma unroll
        for (int r = 0; r < 4; ++r) {
          int rowg = bm * 128 + wm * 64 + i * 16 + lg * 4 + r;
          Out[(size_t)rowg * 2048 + col] = acc[i][j][r] + bv;
        }
      }
  }
#undef ASTAGE
#undef BSTAGE
#undef GREADS
#undef GMFMA
}

// ---------------- flash attention v6 (8 waves x 32 q-rows, QBLK=256) -------
// 512 threads, KVBLK=64, 3-buffer ring (96KB) with depth-2 prefetch:
// counted per-wave vmcnt(4) -> tile t landed, t+1 in flight, t+2 staged after
// barrier into the buffer freed last iter. Grid 256 = exactly 1 block/CU.
// Swapped QK^T (mf=2): lane owns q-row l15 per mf frag; K rows permuted so
// packed P lands directly in PV's A-fragment (zero shuffle). Defer-max THR=8.
__global__ __launch_bounds__(512, 2) void attn_kernel(
    const f16* __restrict__ q, const f16* __restrict__ k,
    const f16* __restrict__ vt, f16* __restrict__ o) {
  const int orig = blockIdx.x;                        // [0,256)
  const int swz = (orig & 7) * 32 + (orig >> 3);      // bijective (256%8==0)
  const int qt = swz & 7, bh = swz >> 3;              // 8 q-tiles of 256 rows
  const int tid = threadIdx.x, lane = tid & 63, w = tid >> 6;  // w in [0,8)
  const int l15 = lane & 15, lg = lane >> 4;
  const f16* Qb = q + (size_t)bh * 262144 + (size_t)qt * 256 * 128;
  const char* Kb = (const char*)(k + (size_t)bh * 262144);
  const char* Vtb = (const char*)(vt + (size_t)bh * 262144);
  __shared__ alignas(16) char sm[98304];  // buf b: K @ b*32768 (16K), V @ +16384

  // Q fragments (B-operand): wave w owns q-rows w*32+mf*16+l15
  f16x8 qf[2][4];
#pragma unroll
  for (int mf = 0; mf < 2; ++mf)
#pragma unroll
    for (int ks = 0; ks < 4; ++ks)
      qf[mf][ks] = *(const f16x8*)(Qb + (w * 32 + mf * 16 + l15) * 128 + ks * 32 + lg * 8);

  f32x4 oacc[2][8];
  float mrow[2], ps[2];
#pragma unroll
  for (int mf = 0; mf < 2; ++mf) {
#pragma unroll
    for (int df = 0; df < 8; ++df) oacc[mf][df] = (f32x4)0.f;
    mrow[mf] = -1e30f; ps[mf] = 0.f;
  }
  const int rA = ((l15 >> 2) << 3) + (l15 & 3);  // K-frag row permutation base

#define STAGE(T, B)                                                          \
  {                                                                          \
    char* Ks_ = sm + (B) * 32768;                                            \
    char* Vs_ = Ks_ + 16384;                                                 \
    _Pragma("unroll") for (int i = 0; i < 2; ++i) {                          \
      int c = i * 8 + w;                                                     \
      int phys = c * 1024 + lane * 16;                                       \
      {                                                                      \
        int row = phys >> 8, pcol = phys & 255;                              \
        int lcol = pcol ^ (SWZ3(row) << 4);                                  \
        gload16(Ks_ + c * 1024, Kb + (size_t)((T) * 64 + row) * 256 + lcol); \
      }                                                                      \
      {                                                                      \
        int row = phys >> 7, pcol = phys & 127;                              \
        int lcol = pcol ^ (SWZV(row) << 4);                                  \
        gload16(Vs_ + c * 1024, Vtb + (size_t)row * 4096 + (T) * 128 + lcol);\
      }                                                                      \
    }                                                                        \
  }

  STAGE(0, 0);
  STAGE(1, 1);
  int cur = 0;      // buffer of tile t
  int nxt2 = 2;     // buffer for tile t+2
  for (int t = 0; t < 32; ++t) {
    // per-wave: tile t's 4 loads done; tile t+1's 4 stay in flight
    if (t < 31)
      asm volatile("s_waitcnt vmcnt(4)" ::: "memory");
    else
      asm volatile("s_waitcnt vmcnt(0)" ::: "memory");
    __builtin_amdgcn_s_barrier();  // all waves: tile t in LDS; buf nxt2 free
    if (t < 30) STAGE(t + 2, nxt2);  // overlaps with compute below
    const char* Ks = sm + cur * 32768;
    const char* Vs = Ks + 16384;

    // ---- QK^T swapped: s[mf][nf] = S[kv'][q] -------------------------------
    f32x4 s[2][4];
#pragma unroll
    for (int mf = 0; mf < 2; ++mf)
#pragma unroll
      for (int nf = 0; nf < 4; ++nf) s[mf][nf] = (f32x4)0.f;
    __builtin_amdgcn_s_setprio(1);
#pragma unroll
    for (int ks = 0; ks < 4; ++ks) {
      f16x8 kf[4];
#pragma unroll
      for (int nf = 0; nf < 4; ++nf) {
        int row = ((nf & 1) << 5) + ((nf >> 1) << 2) + rA;  // permuted kv row
        int colb = (ks * 64 + lg * 16) ^ (SWZ3(row) << 4);
        kf[nf] = *(const f16x8*)(Ks + row * 256 + colb);
      }
#pragma unroll
      for (int mf = 0; mf < 2; ++mf)
#pragma unroll
        for (int nf = 0; nf < 4; ++nf)
          s[mf][nf] = __builtin_amdgcn_mfma_f32_16x16x32_f16(kf[nf], qf[mf][ks], s[mf][nf], 0, 0, 0);
    }
    __builtin_amdgcn_s_setprio(0);
    // lane (l15,lg) reg r of s[mf][nf] = S[kv=(nf&1)*32+lg*8+(nf>>1)*4+r][q-row l15]

    // ---- online softmax (defer-max), P packed in registers -----------------
    unsigned int pk[2][2][4];  // [mf][kvs][word] -> PV A-frag direct
#pragma unroll
    for (int mf = 0; mf < 2; ++mf) {
      float m01 = fmaxf(fmaxf(s[mf][0][0], s[mf][0][1]),
                        fmaxf(s[mf][0][2], s[mf][0][3]));
      float m23 = fmaxf(fmaxf(s[mf][1][0], s[mf][1][1]),
                        fmaxf(s[mf][1][2], s[mf][1][3]));
      float m45 = fmaxf(fmaxf(s[mf][2][0], s[mf][2][1]),
                        fmaxf(s[mf][2][2], s[mf][2][3]));
      float m67 = fmaxf(fmaxf(s[mf][3][0], s[mf][3][1]),
                        fmaxf(s[mf][3][2], s[mf][3][3]));
      float mx = fmaxf(fmaxf(m01, m23), fmaxf(m45, m67));
      mx = fmaxf(mx, __shfl_xor(mx, 16));
      mx = fmaxf(mx, __shfl_xor(mx, 32));
      if (!__all(mx <= mrow[mf] + 8.f)) {  // rare after first tile
        float mnew = fmaxf(mrow[mf], mx);
        float sc = exp2f(mrow[mf] - mnew);
        mrow[mf] = mnew;
        ps[mf] *= sc;
#pragma unroll
        for (int r = 0; r < 4; ++r) {
          float scr = __shfl(sc, (lane & 48) | (lg * 4 + r));
#pragma unroll
          for (int df = 0; df < 8; ++df) oacc[mf][df][r] *= scr;
        }
      }
      float m = mrow[mf];
      float psum = 0.f;
#pragma unroll
      for (int nf = 0; nf < 4; ++nf)
#pragma unroll
        for (int h = 0; h < 2; ++h) {
          float p0 = exp2f(s[mf][nf][2 * h] - m);
          float p1 = exp2f(s[mf][nf][2 * h + 1] - m);
          psum += p0 + p1;
          pk[mf][nf & 1][(nf >> 1) * 2 + h] =
              __builtin_bit_cast(unsigned int, __builtin_amdgcn_cvt_pkrtz(p0, p1));
        }
      ps[mf] += psum;  // cross-lane reduction deferred to epilogue
    }

    // ---- PV: oacc += P[32 x 64] @ V[64 x 128] ------------------------------
    __builtin_amdgcn_s_setprio(1);
#pragma unroll
    for (int kvs = 0; kvs < 2; ++kvs) {
      f16x8 pa[2];
#pragma unroll
      for (int mf = 0; mf < 2; ++mf)
        pa[mf] = __builtin_bit_cast(f16x8, *(const u32x4*)pk[mf][kvs]);
#pragma unroll
      for (int df = 0; df < 8; ++df) {
        int row = df * 16 + l15;
        int colb = (kvs * 64 + lg * 16) ^ (SWZV(row) << 4);
        f16x8 vb = *(const f16x8*)(Vs + row * 128 + colb);
#pragma unroll
        for (int mf = 0; mf < 2; ++mf)
          oacc[mf][df] = __builtin_amdgcn_mfma_f32_16x16x32_f16(pa[mf], vb, oacc[mf][df], 0, 0, 0);
      }
    }
    __builtin_amdgcn_s_setprio(0);
    cur = cur == 2 ? 0 : cur + 1;
    nxt2 = nxt2 == 2 ? 0 : nxt2 + 1;
  }

  // epilogue: reduce l across lanes, normalize, write o [b,l,h*128+d] f16
  const int b_ = bh >> 4, h_ = bh & 15;
  f16* Ob = o + (size_t)b_ * 4194304 + (size_t)qt * 256 * 2048 + h_ * 128;
#pragma unroll
  for (int mf = 0; mf < 2; ++mf) {
    float lr = ps[mf];
    lr += __shfl_xor(lr, 16);
    lr += __shfl_xor(lr, 32);
    float inv = 1.f / lr;  // for q-row l15
#pragma unroll
    for (int r = 0; r < 4; ++r) {
      float invr = __shfl(inv, (lane & 48) | (lg * 4 + r));
      int rl = w * 32 + mf * 16 + lg * 4 + r;
#pragma unroll
      for (int df = 0; df < 8; ++df)
        Ob[(size_t)rl * 2048 + df * 16 + l15] = (f16)(oacc[mf][df][r] * invr);
    }
  }
#undef STAGE
}

// ---------------------------------------------------------------------------
extern "C" void kernel_launch(void* const* d_in, const int* in_sizes, int n_in,
                              void* d_out, int out_size, void* d_ws, size_t ws_size,
                              hipStream_t stream) {
  const float* xq = (const float*)d_in[0];
  const float* xk = (const float*)d_in[1];
  const float* xv = (const float*)d_in[2];
  const float* Wq = (const float*)d_in[3];
  const float* bq = (const float*)d_in[4];
  const float* Wk = (const float*)d_in[5];
  const float* bk = (const float*)d_in[6];
  const float* Wv = (const float*)d_in[7];
  const float* bv = (const float*)d_in[8];
  const float* Wo = (const float*)d_in[9];
  const float* bo = (const float*)d_in[10];

  // ws layout (bytes), total 128 MiB:
  //   [0,50331648)        xh: x_q/x_k/x_v f16 (3 x 16 MiB)
  //   [50331648,83886080) wt: WqT/WkT/WvT/WoT f16 (4 x 8 MiB)
  //   [83886080,134217728) qkv: q/k/v^T head-split f16 (3 x 16 MiB)
  //       (z==2 slot holds V^T [b,h,d,l] -- written directly by the GEMM)
  //   oatt aliases xh_k region (dead after QKV GEMM).
  char* ws = (char*)d_ws;
  f16* xh   = (f16*)(ws);
  f16* wt   = (f16*)(ws + 50331648);
  f16* qkv  = (f16*)(ws + 83886080);
  f16* oatt = (f16*)(ws + 16777216);  // alias: x_k f16 region
  float* outp = (float*)d_out;

  hipLaunchKernelGGL(cvt_x_kernel, dim3(4096, 1, 3), dim3(256), 0, stream,
                     xq, xk, xv, xh);
  hipLaunchKernelGGL(cvt_w_kernel, dim3(32, 32, 4), dim3(256), 0, stream,
                     Wq, Wk, Wv, Wo, wt);
  hipLaunchKernelGGL((gemm128_kernel<0>), dim3(768), dim3(512), 0, stream,
                     xh, wt, (void*)qkv, bq, bk, bv);
  hipLaunchKernelGGL(attn_kernel, dim3(256), dim3(512), 0, stream,
                     qkv, qkv + (size_t)8388608, qkv + (size_t)2 * 8388608, oatt);
  hipLaunchKernelGGL((gemm128_kernel<1>), dim3(256), dim3(512), 0, stream,
                     oatt, wt + (size_t)3 * 4194304, (void*)outp, bo, bo, bo);
}